// Round 1
// baseline (200.955 us; speedup 1.0000x reference)
//
#include <hip/hip_runtime.h>
#include <hip/hip_bf16.h>
#include <math.h>

#define N 4096
#define K 2048
#define MARGIN 0.3f

typedef float f32x4 __attribute__((ext_vector_type(4)));
typedef __bf16 bf16x8 __attribute__((ext_vector_type(8)));

// ---------------------------------------------------------------------------
// Kernel 1: fp32 -> bf16 convert, per-row sum-of-squares, init ap/an arrays.
// One block per row, 256 threads, 8 elements/thread.
// ---------------------------------------------------------------------------
__global__ __launch_bounds__(256) void convert_kernel(
    const float* __restrict__ X, __bf16* __restrict__ Xb,
    float* __restrict__ sq, unsigned int* __restrict__ ap,
    unsigned int* __restrict__ an) {
  int row = blockIdx.x;
  int t = threadIdx.x;
  const float* xr = X + (size_t)row * K;
  __bf16* xbr = Xb + (size_t)row * K;

  float4 v0 = ((const float4*)xr)[t * 2 + 0];
  float4 v1 = ((const float4*)xr)[t * 2 + 1];

  float s = v0.x * v0.x + v0.y * v0.y + v0.z * v0.z + v0.w * v0.w +
            v1.x * v1.x + v1.y * v1.y + v1.z * v1.z + v1.w * v1.w;

  bf16x8 b;
  b[0] = (__bf16)v0.x; b[1] = (__bf16)v0.y; b[2] = (__bf16)v0.z; b[3] = (__bf16)v0.w;
  b[4] = (__bf16)v1.x; b[5] = (__bf16)v1.y; b[6] = (__bf16)v1.z; b[7] = (__bf16)v1.w;
  ((bf16x8*)xbr)[t] = b;

  // wave (64) reduce, then cross-wave via LDS
  #pragma unroll
  for (int m = 32; m; m >>= 1) s += __shfl_xor(s, m);
  __shared__ float wred[4];
  if ((t & 63) == 0) wred[t >> 6] = s;
  __syncthreads();
  if (t == 0) {
    sq[row] = wred[0] + wred[1] + wred[2] + wred[3];
    ap[row] = 0u;           // identity for max of non-negative floats
    an[row] = 0x7f800000u;  // +inf, identity for min
  }
}

// ---------------------------------------------------------------------------
// Kernel 2: tiled bf16 MFMA Gram matrix + fused distance/mask/row-reduction.
// 128x128 block tile, 4 waves each computing a 64x64 quadrant as 4x4 tiles of
// 16x16x32 MFMA. global_load_lds width=16 staging (unpadded [128][32] LDS).
// ---------------------------------------------------------------------------
__device__ __forceinline__ void glds16(const void* g, void* l) {
  __builtin_amdgcn_global_load_lds(
      (const __attribute__((address_space(1))) void*)g,
      (__attribute__((address_space(3))) void*)l, 16, 0, 0);
}

__global__ __launch_bounds__(256) void gemm_reduce_kernel(
    const __bf16* __restrict__ Xb, const float* __restrict__ sq,
    const int* __restrict__ tg, unsigned int* __restrict__ ap,
    unsigned int* __restrict__ an) {
  __shared__ __align__(16) __bf16 sA[128 * 32];
  __shared__ __align__(16) __bf16 sB[128 * 32];

  int bi = blockIdx.x & 31;
  int bj = blockIdx.x >> 5;
  int i0 = bi * 128, j0 = bj * 128;

  int t = threadIdx.x;
  int w = t >> 6, l = t & 63;
  int wi = w >> 1, wj = w & 1;
  int quad = l >> 4, lr = l & 15;

  f32x4 acc[4][4];
  #pragma unroll
  for (int a = 0; a < 4; a++)
    #pragma unroll
    for (int b = 0; b < 4; b++) acc[a][b] = (f32x4)0.f;

  // staging addressing: round r, thread t covers LDS bytes (r*4096 + t*16)
  int bo0 = t * 16;
  int bo1 = bo0 + 4096;
  int row0 = bo0 >> 6, col0 = (bo0 & 63) >> 1;
  int row1 = bo1 >> 6, col1 = (bo1 & 63) >> 1;

  const __bf16* gA0 = Xb + (size_t)(i0 + row0) * K + col0;
  const __bf16* gA1 = Xb + (size_t)(i0 + row1) * K + col1;
  const __bf16* gB0 = Xb + (size_t)(j0 + row0) * K + col0;
  const __bf16* gB1 = Xb + (size_t)(j0 + row1) * K + col1;

  char* lA0 = (char*)sA + bo0;
  char* lA1 = (char*)sA + bo1;
  char* lB0 = (char*)sB + bo0;
  char* lB1 = (char*)sB + bo1;

  for (int kk = 0; kk < K; kk += 32) {
    __syncthreads();
    glds16(gA0 + kk, lA0);
    glds16(gA1 + kk, lA1);
    glds16(gB0 + kk, lB0);
    glds16(gB1 + kk, lB1);
    __syncthreads();

    bf16x8 afr[4], bfr[4];
    #pragma unroll
    for (int ti = 0; ti < 4; ti++) {
      int arow = wi * 64 + ti * 16 + lr;
      afr[ti] = *(const bf16x8*)(sA + arow * 32 + quad * 8);
    }
    #pragma unroll
    for (int tj = 0; tj < 4; tj++) {
      int brow = wj * 64 + tj * 16 + lr;
      bfr[tj] = *(const bf16x8*)(sB + brow * 32 + quad * 8);
    }
    #pragma unroll
    for (int ti = 0; ti < 4; ti++)
      #pragma unroll
      for (int tj = 0; tj < 4; tj++)
        acc[ti][tj] = __builtin_amdgcn_mfma_f32_16x16x32_bf16(
            afr[ti], bfr[tj], acc[ti][tj], 0, 0, 0);
  }

  // Epilogue: dist + masks + per-row reduction.
  // C/D layout: col = lane&15, row = quad*4 + reg.
  int jg[4]; float sqj[4]; int cj[4];
  #pragma unroll
  for (int tj = 0; tj < 4; tj++) {
    jg[tj] = j0 + wj * 64 + tj * 16 + lr;
    sqj[tj] = sq[jg[tj]];
    cj[tj] = tg[jg[tj]];
  }

  #pragma unroll
  for (int ti = 0; ti < 4; ti++) {
    #pragma unroll
    for (int r = 0; r < 4; r++) {
      int ig = i0 + wi * 64 + ti * 16 + quad * 4 + r;
      float sqi = sq[ig];
      int ci = tg[ig];
      float apm = 0.f, anm = INFINITY;
      #pragma unroll
      for (int tj = 0; tj < 4; tj++) {
        float g = acc[ti][tj][r];
        float d2 = sqi + sqj[tj] - 2.f * g;
        float d = sqrtf(fmaxf(d2, 1e-12f));
        bool same = (ci == cj[tj]);
        if (same) {
          apm = fmaxf(apm, d);
        } else if (ci == 0 || cj[tj] == 0) {
          anm = fminf(anm, d);
        }
      }
      // butterfly over the 16-lane column group (same ig for all 16 lanes)
      #pragma unroll
      for (int m = 1; m < 16; m <<= 1) {
        apm = fmaxf(apm, __shfl_xor(apm, m));
        anm = fminf(anm, __shfl_xor(anm, m));
      }
      if (lr == 0) {
        atomicMax(ap + ig, __float_as_uint(apm));
        atomicMin(an + ig, __float_as_uint(anm));
      }
    }
  }
}

// ---------------------------------------------------------------------------
// Kernel 3: row0_has_zero + mean(relu(ap - an + margin))
// ---------------------------------------------------------------------------
__global__ __launch_bounds__(256) void loss_kernel(
    const unsigned int* __restrict__ ap, const unsigned int* __restrict__ an,
    const int* __restrict__ tg, float* __restrict__ out) {
  int t = threadIdx.x;
  __shared__ int flagred;
  if (t == 0) flagred = 0;
  __syncthreads();

  int t0 = tg[0];
  int flag = 0;
  for (int j = t; j < N; j += 256) {
    int tj = tg[j];
    if ((tj != t0) && (t0 == 0 || tj == 0)) flag = 1;
  }
  if (flag) atomicOr(&flagred, 1);
  __syncthreads();
  int has = flagred;

  float s = 0.f;
  for (int i = t; i < N; i += 256) {
    float apf = __uint_as_float(ap[i]);
    float anf = has ? __uint_as_float(an[i]) : 0.f;
    s += fmaxf(apf - anf + MARGIN, 0.f);  // an=+inf -> -inf -> 0, no NaN
  }
  #pragma unroll
  for (int m = 32; m; m >>= 1) s += __shfl_xor(s, m);
  __shared__ float wred[4];
  if ((t & 63) == 0) wred[t >> 6] = s;
  __syncthreads();
  if (t == 0) out[0] = (wred[0] + wred[1] + wred[2] + wred[3]) / (float)N;
}

// ---------------------------------------------------------------------------
extern "C" void kernel_launch(void* const* d_in, const int* in_sizes, int n_in,
                              void* d_out, int out_size, void* d_ws,
                              size_t ws_size, hipStream_t stream) {
  const float* X = (const float*)d_in[0];
  const int* tg = (const int*)d_in[1];
  float* out = (float*)d_out;

  char* ws = (char*)d_ws;
  __bf16* Xb = (__bf16*)ws;                                   // 16 MiB
  float* sq = (float*)(ws + (size_t)N * K * 2);               // 16 KiB
  unsigned int* ap = (unsigned int*)(ws + (size_t)N * K * 2 + (size_t)N * 4);
  unsigned int* an = (unsigned int*)(ws + (size_t)N * K * 2 + (size_t)2 * N * 4);

  convert_kernel<<<N, 256, 0, stream>>>(X, Xb, sq, ap, an);
  gemm_reduce_kernel<<<dim3(32 * 32), 256, 0, stream>>>(Xb, sq, tg, ap, an);
  loss_kernel<<<1, 256, 0, stream>>>(ap, an, tg, out);
}

// Round 2
// 153.261 us; speedup vs baseline: 1.3112x; 1.3112x over previous
//
#include <hip/hip_runtime.h>
#include <hip/hip_bf16.h>
#include <math.h>

#define N 4096
#define K 2048
#define NC 32
#define MARGIN 0.3f

typedef float f32x4 __attribute__((ext_vector_type(4)));
typedef __bf16 bf16x8 __attribute__((ext_vector_type(8)));

__device__ __forceinline__ void glds16(const void* g, void* l) {
  __builtin_amdgcn_global_load_lds(
      (const __attribute__((address_space(1))) void*)g,
      (__attribute__((address_space(3))) void*)l, 16, 0, 0);
}

__device__ __forceinline__ int imin(int a, int b) { return a < b ? a : b; }

// ---------------------------------------------------------------------------
// Kernel 0: class histogram -> offsets/cursors + row0_has_zero flag.
// ---------------------------------------------------------------------------
__global__ __launch_bounds__(256) void hist_kernel(
    const int* __restrict__ tg, int* __restrict__ cnt, int* __restrict__ off,
    int* __restrict__ cursor, int* __restrict__ flag) {
  __shared__ int h[NC];
  int t = threadIdx.x;
  if (t < NC) h[t] = 0;
  __syncthreads();
  for (int i = t; i < N; i += 256) atomicAdd(&h[tg[i]], 1);
  __syncthreads();
  if (t == 0) {
    int acc = 0;
    for (int c = 0; c < NC; c++) {
      cnt[c] = h[c];
      off[c] = acc;
      cursor[c] = acc;
      acc += h[c];
    }
    int t0 = tg[0];
    flag[0] = (t0 == 0) ? (N - h[0] > 0) : (h[0] > 0);
  }
}

// ---------------------------------------------------------------------------
// Kernel 1: fp32 -> bf16 convert + class-sorted scatter + sum-of-squares +
// ap/an init. One block per original row.
// ---------------------------------------------------------------------------
__global__ __launch_bounds__(256) void convert_kernel(
    const float* __restrict__ X, const int* __restrict__ tg,
    __bf16* __restrict__ Xg, float* __restrict__ sqg,
    unsigned int* __restrict__ ap, unsigned int* __restrict__ an,
    int* __restrict__ cursor) {
  int row = blockIdx.x;
  int t = threadIdx.x;
  const float* xr = X + (size_t)row * K;

  float4 v0 = ((const float4*)xr)[t * 2 + 0];
  float4 v1 = ((const float4*)xr)[t * 2 + 1];

  float s = v0.x * v0.x + v0.y * v0.y + v0.z * v0.z + v0.w * v0.w +
            v1.x * v1.x + v1.y * v1.y + v1.z * v1.z + v1.w * v1.w;

  bf16x8 b;
  b[0] = (__bf16)v0.x; b[1] = (__bf16)v0.y; b[2] = (__bf16)v0.z; b[3] = (__bf16)v0.w;
  b[4] = (__bf16)v1.x; b[5] = (__bf16)v1.y; b[6] = (__bf16)v1.z; b[7] = (__bf16)v1.w;

  #pragma unroll
  for (int m = 32; m; m >>= 1) s += __shfl_xor(s, m);

  __shared__ float wred[4];
  __shared__ int spos;
  if ((t & 63) == 0) wred[t >> 6] = s;
  if (t == 0) spos = atomicAdd(&cursor[tg[row]], 1);
  __syncthreads();
  int pos = spos;

  ((bf16x8*)(Xg + (size_t)pos * K))[t] = b;
  if (t == 0) {
    sqg[pos] = wred[0] + wred[1] + wred[2] + wred[3];
    ap[pos] = 0u;           // identity for max of non-negative floats
    an[pos] = 0x7f800000u;  // +inf
  }
}

// ---------------------------------------------------------------------------
// Kernel 2: class-bucketed 128x128 MFMA tiles, BK=64, swizzled LDS.
//   blocks [0,128):   diag — class c = b>>2, 2x2 sub-tiles; same-class -> ap.
//   blocks [128,192): cross — class0 rows x nonzero rows; both sides -> an.
// Partial tiles handled by clamping rows into the valid range (duplicates of
// real candidates are no-ops under max/min).
// ---------------------------------------------------------------------------
__global__ __launch_bounds__(256) void gemm_reduce_kernel(
    const __bf16* __restrict__ Xg, const float* __restrict__ sqg,
    const int* __restrict__ cnt, const int* __restrict__ off,
    unsigned int* __restrict__ ap, unsigned int* __restrict__ an) {
  int b = blockIdx.x;
  int i0g, iend, j0g, jend;
  bool diag;
  if (b < 128) {
    int c = b >> 2;
    int sti = (b >> 1) & 1, stj = b & 1;
    int o = off[c], n = cnt[c];
    if (n == 0 || sti * 128 >= n || stj * 128 >= n) return;
    i0g = o + sti * 128; iend = o + n;
    j0g = o + stj * 128; jend = o + n;
    diag = true;
  } else {
    int idx = b - 128;
    int it = idx >> 5, jt = idx & 31;
    int n0 = cnt[0];
    if (n0 == 0 || it * 128 >= n0) return;
    int j0 = n0 + jt * 128;
    if (j0 >= N) return;
    i0g = it * 128; iend = n0;
    j0g = j0; jend = N;
    diag = false;
  }

  __shared__ __align__(16) __bf16 sA[128 * 64];
  __shared__ __align__(16) __bf16 sB[128 * 64];

  int t = threadIdx.x;
  int w = t >> 6, l = t & 63;
  int wi = w >> 1, wj = w & 1;
  int quad = l >> 4, lr = l & 15;

  // Staging: thread t fills LDS slot (row_l = r*32 + t>>3, cb_l = t&7) from
  // global column-block cb_g = cb_l ^ (row_l & 7)  (XOR bank swizzle).
  const char* gA[4]; const char* gB[4];
  char* lA[4]; char* lB[4];
  int rr = t >> 3, cbl = t & 7;
  #pragma unroll
  for (int r = 0; r < 4; r++) {
    int row_l = r * 32 + rr;
    int cbg = cbl ^ (row_l & 7);
    int ra = imin(i0g + row_l, iend - 1);
    int rb = imin(j0g + row_l, jend - 1);
    gA[r] = (const char*)(Xg + (size_t)ra * K) + cbg * 16;
    gB[r] = (const char*)(Xg + (size_t)rb * K) + cbg * 16;
    lA[r] = (char*)sA + r * 4096 + t * 16;
    lB[r] = (char*)sB + r * 4096 + t * 16;
  }

  // Fragment LDS byte offsets (undo the swizzle: row&7 == lr&7 here).
  int aoff[4][2], boff[4][2];
  #pragma unroll
  for (int ti = 0; ti < 4; ti++)
    #pragma unroll
    for (int h = 0; h < 2; h++) {
      int sw = (((h << 2) + quad) ^ (lr & 7)) << 4;
      aoff[ti][h] = (wi * 64 + ti * 16 + lr) * 128 + sw;
      boff[ti][h] = (wj * 64 + ti * 16 + lr) * 128 + sw;
    }

  f32x4 acc[4][4];
  #pragma unroll
  for (int a = 0; a < 4; a++)
    #pragma unroll
    for (int c2 = 0; c2 < 4; c2++) acc[a][c2] = (f32x4)0.f;

  for (int kk = 0; kk < K; kk += 64) {
    __syncthreads();
    #pragma unroll
    for (int r = 0; r < 4; r++) {
      glds16(gA[r] + kk * 2, lA[r]);
      glds16(gB[r] + kk * 2, lB[r]);
    }
    __syncthreads();

    bf16x8 afr[4][2], bfr[4][2];
    #pragma unroll
    for (int ti = 0; ti < 4; ti++)
      #pragma unroll
      for (int h = 0; h < 2; h++) {
        afr[ti][h] = *(const bf16x8*)((const char*)sA + aoff[ti][h]);
        bfr[ti][h] = *(const bf16x8*)((const char*)sB + boff[ti][h]);
      }

    #pragma unroll
    for (int ti = 0; ti < 4; ti++)
      #pragma unroll
      for (int tj = 0; tj < 4; tj++) {
        acc[ti][tj] = __builtin_amdgcn_mfma_f32_16x16x32_bf16(
            afr[ti][0], bfr[tj][0], acc[ti][tj], 0, 0, 0);
        acc[ti][tj] = __builtin_amdgcn_mfma_f32_16x16x32_bf16(
            afr[ti][1], bfr[tj][1], acc[ti][tj], 0, 0, 0);
      }
  }

  // Epilogue. C/D layout: col = lane&15 (j), row = quad*4 + reg (i).
  int jgc[4]; float sqj[4];
  #pragma unroll
  for (int tj = 0; tj < 4; tj++) {
    int jg = j0g + wj * 64 + tj * 16 + lr;
    jgc[tj] = imin(jg, jend - 1);
    sqj[tj] = sqg[jgc[tj]];
  }

  if (diag) {
    #pragma unroll
    for (int ti = 0; ti < 4; ti++) {
      #pragma unroll
      for (int r = 0; r < 4; r++) {
        int ig = i0g + wi * 64 + ti * 16 + quad * 4 + r;
        int igc = imin(ig, iend - 1);
        float sqi = sqg[igc];
        float apm = 0.f;
        #pragma unroll
        for (int tj = 0; tj < 4; tj++) {
          float d2 = sqi + sqj[tj] - 2.f * acc[ti][tj][r];
          float d = sqrtf(fmaxf(d2, 1e-12f));
          apm = fmaxf(apm, d);
        }
        #pragma unroll
        for (int m = 1; m < 16; m <<= 1) apm = fmaxf(apm, __shfl_xor(apm, m));
        if (lr == 0) atomicMax(ap + igc, __float_as_uint(apm));
      }
    }
  } else {
    float colmin[4] = {INFINITY, INFINITY, INFINITY, INFINITY};
    #pragma unroll
    for (int ti = 0; ti < 4; ti++) {
      #pragma unroll
      for (int r = 0; r < 4; r++) {
        int ig = i0g + wi * 64 + ti * 16 + quad * 4 + r;
        int igc = imin(ig, iend - 1);
        float sqi = sqg[igc];
        float anm = INFINITY;
        #pragma unroll
        for (int tj = 0; tj < 4; tj++) {
          float d2 = sqi + sqj[tj] - 2.f * acc[ti][tj][r];
          float d = sqrtf(fmaxf(d2, 1e-12f));
          anm = fminf(anm, d);
          colmin[tj] = fminf(colmin[tj], d);
        }
        #pragma unroll
        for (int m = 1; m < 16; m <<= 1) anm = fminf(anm, __shfl_xor(anm, m));
        if (lr == 0) atomicMin(an + igc, __float_as_uint(anm));
      }
    }
    #pragma unroll
    for (int tj = 0; tj < 4; tj++) {
      float v = colmin[tj];
      v = fminf(v, __shfl_xor(v, 16));
      v = fminf(v, __shfl_xor(v, 32));
      if (quad == 0) atomicMin(an + jgc[tj], __float_as_uint(v));
    }
  }
}

// ---------------------------------------------------------------------------
// Kernel 3: mean(relu(ap - an + margin)), an gated by row0_has_zero flag.
// ---------------------------------------------------------------------------
__global__ __launch_bounds__(256) void loss_kernel(
    const unsigned int* __restrict__ ap, const unsigned int* __restrict__ an,
    const int* __restrict__ flag, float* __restrict__ out) {
  int t = threadIdx.x;
  int has = flag[0];
  float s = 0.f;
  for (int i = t; i < N / 4; i += 256) {
    uint4 a4 = ((const uint4*)ap)[i];
    uint4 n4 = ((const uint4*)an)[i];
    float a0 = __uint_as_float(a4.x), a1 = __uint_as_float(a4.y);
    float a2 = __uint_as_float(a4.z), a3 = __uint_as_float(a4.w);
    float b0 = has ? __uint_as_float(n4.x) : 0.f;
    float b1 = has ? __uint_as_float(n4.y) : 0.f;
    float b2 = has ? __uint_as_float(n4.z) : 0.f;
    float b3 = has ? __uint_as_float(n4.w) : 0.f;
    s += fmaxf(a0 - b0 + MARGIN, 0.f);
    s += fmaxf(a1 - b1 + MARGIN, 0.f);
    s += fmaxf(a2 - b2 + MARGIN, 0.f);
    s += fmaxf(a3 - b3 + MARGIN, 0.f);
  }
  #pragma unroll
  for (int m = 32; m; m >>= 1) s += __shfl_xor(s, m);
  __shared__ float wred[4];
  if ((t & 63) == 0) wred[t >> 6] = s;
  __syncthreads();
  if (t == 0) out[0] = (wred[0] + wred[1] + wred[2] + wred[3]) / (float)N;
}

// ---------------------------------------------------------------------------
extern "C" void kernel_launch(void* const* d_in, const int* in_sizes, int n_in,
                              void* d_out, int out_size, void* d_ws,
                              size_t ws_size, hipStream_t stream) {
  const float* X = (const float*)d_in[0];
  const int* tg = (const int*)d_in[1];
  float* out = (float*)d_out;

  char* ws = (char*)d_ws;
  __bf16* Xg = (__bf16*)ws;
  size_t o = (size_t)N * K * 2;
  float* sqg = (float*)(ws + o); o += (size_t)N * 4;
  unsigned int* ap = (unsigned int*)(ws + o); o += (size_t)N * 4;
  unsigned int* an = (unsigned int*)(ws + o); o += (size_t)N * 4;
  int* cnt = (int*)(ws + o); o += NC * 4;
  int* off = (int*)(ws + o); o += NC * 4;
  int* cur = (int*)(ws + o); o += NC * 4;
  int* flag = (int*)(ws + o); o += 4;

  hist_kernel<<<1, 256, 0, stream>>>(tg, cnt, off, cur, flag);
  convert_kernel<<<N, 256, 0, stream>>>(X, tg, Xg, sqg, ap, an, cur);
  gemm_reduce_kernel<<<192, 256, 0, stream>>>(Xg, sqg, cnt, off, ap, an);
  loss_kernel<<<1, 256, 0, stream>>>(ap, an, flag, out);
}

// Round 3
// 141.921 us; speedup vs baseline: 1.4160x; 1.0799x over previous
//
#include <hip/hip_runtime.h>
#include <hip/hip_bf16.h>
#include <math.h>

#define N 4096
#define K 2048
#define NC 32
#define MARGIN 0.3f

#define BK 128           // K elements per pipeline stage
#define NITER (K / BK)   // 16
#define DIAG_BLOCKS 288  // 32 classes x 3x3 sub-tiles of 64
#define CROSS_BLOCKS 192 // 3 row-tiles x 64 col-tiles
#define GRID (DIAG_BLOCKS + CROSS_BLOCKS)

typedef float f32x4 __attribute__((ext_vector_type(4)));
typedef __bf16 bf16x8 __attribute__((ext_vector_type(8)));

__device__ __forceinline__ void glds16(const void* g, void* l) {
  __builtin_amdgcn_global_load_lds(
      (const __attribute__((address_space(1))) void*)g,
      (__attribute__((address_space(3))) void*)l, 16, 0, 0);
}

__device__ __forceinline__ int imin(int a, int b) { return a < b ? a : b; }

// ---------------------------------------------------------------------------
// Kernel 0: class histogram -> offsets/cursors, row0_has_zero flag, done=0.
// ---------------------------------------------------------------------------
__global__ __launch_bounds__(256) void hist_kernel(
    const int* __restrict__ tg, int* __restrict__ cnt, int* __restrict__ off,
    int* __restrict__ cursor, int* __restrict__ flag, int* __restrict__ done) {
  __shared__ int h[NC];
  int t = threadIdx.x;
  if (t < NC) h[t] = 0;
  __syncthreads();
  const int4* tg4 = (const int4*)tg;
  for (int i = t; i < N / 4; i += 256) {
    int4 v = tg4[i];
    atomicAdd(&h[v.x], 1); atomicAdd(&h[v.y], 1);
    atomicAdd(&h[v.z], 1); atomicAdd(&h[v.w], 1);
  }
  __syncthreads();
  if (t == 0) {
    int acc = 0;
    for (int c = 0; c < NC; c++) {
      cnt[c] = h[c];
      off[c] = acc;
      cursor[c] = acc;
      acc += h[c];
    }
    int t0 = tg[0];
    flag[0] = (t0 == 0) ? (N - h[0] > 0) : (h[0] > 0);
    done[0] = 0;
  }
}

// ---------------------------------------------------------------------------
// Kernel 1: fp32 -> bf16 convert + class-sorted scatter + sum-of-squares +
// ap/an init. One block per original row.
// ---------------------------------------------------------------------------
__global__ __launch_bounds__(256) void convert_kernel(
    const float* __restrict__ X, const int* __restrict__ tg,
    __bf16* __restrict__ Xg, float* __restrict__ sqg,
    unsigned int* __restrict__ ap, unsigned int* __restrict__ an,
    int* __restrict__ cursor) {
  int row = blockIdx.x;
  int t = threadIdx.x;
  const float* xr = X + (size_t)row * K;

  float4 v0 = ((const float4*)xr)[t * 2 + 0];
  float4 v1 = ((const float4*)xr)[t * 2 + 1];

  float s = v0.x * v0.x + v0.y * v0.y + v0.z * v0.z + v0.w * v0.w +
            v1.x * v1.x + v1.y * v1.y + v1.z * v1.z + v1.w * v1.w;

  bf16x8 b;
  b[0] = (__bf16)v0.x; b[1] = (__bf16)v0.y; b[2] = (__bf16)v0.z; b[3] = (__bf16)v0.w;
  b[4] = (__bf16)v1.x; b[5] = (__bf16)v1.y; b[6] = (__bf16)v1.z; b[7] = (__bf16)v1.w;

  #pragma unroll
  for (int m = 32; m; m >>= 1) s += __shfl_xor(s, m);

  __shared__ float wred[4];
  __shared__ int spos;
  if ((t & 63) == 0) wred[t >> 6] = s;
  if (t == 0) spos = atomicAdd(&cursor[tg[row]], 1);
  __syncthreads();
  int pos = spos;

  ((bf16x8*)(Xg + (size_t)pos * K))[t] = b;
  if (t == 0) {
    sqg[pos] = wred[0] + wred[1] + wred[2] + wred[3];
    ap[pos] = 0u;           // identity for max of non-negative floats
    an[pos] = 0x7f800000u;  // +inf
  }
}

// ---------------------------------------------------------------------------
// Kernel 2: class-bucketed 64x64 MFMA tiles, BK=128, double-buffered async
// global_load_lds pipeline with raw s_barrier + manual vmcnt (prefetch stays
// in flight across the barrier). XOR-swizzled LDS. Last block (ticket) does
// the final loss reduction.
// ---------------------------------------------------------------------------
__global__ __launch_bounds__(256) void gemm_reduce_kernel(
    const __bf16* __restrict__ Xg, const float* __restrict__ sqg,
    const int* __restrict__ cnt, const int* __restrict__ off,
    unsigned int* __restrict__ ap, unsigned int* __restrict__ an,
    const int* __restrict__ flag, int* __restrict__ done,
    float* __restrict__ out) {
  __shared__ __align__(16) __bf16 sA[2][64 * BK];  // 2 x 16 KiB
  __shared__ __align__(16) __bf16 sB[2][64 * BK];
  __shared__ int s_islast;
  __shared__ float wred[4];

  int b = blockIdx.x;
  int t = threadIdx.x;

  bool active = true, diag = true;
  int i0g = 0, iend = 1, j0g = 0, jend = 1;
  if (b < DIAG_BLOCKS) {
    int c = b / 9, sub = b % 9;
    int sti = sub / 3, stj = sub % 3;
    int o = off[c], n = cnt[c];
    if (n == 0 || sti * 64 >= n || stj * 64 >= n) active = false;
    i0g = o + sti * 64; iend = o + n;
    j0g = o + stj * 64; jend = o + n;
  } else {
    int idx = b - DIAG_BLOCKS;
    int it = idx >> 6, jt = idx & 63;
    int n0 = cnt[0];
    int j0 = n0 + jt * 64;
    if (n0 == 0 || it * 64 >= n0 || j0 >= N) active = false;
    i0g = it * 64; iend = n0;
    j0g = j0; jend = N;
    diag = false;
  }

  if (active) {
    int w = t >> 6, l = t & 63;
    int wi = w >> 1, wj = w & 1;
    int quad = l >> 4, lr = l & 15;

    // Staging: thread t fills LDS (row_l = r*16 + t>>4, cb_l = t&15) from
    // global col-block cb_g = cb_l ^ (row_l & 15). row_l&15 == t>>4.
    const char* gA[4]; const char* gB[4];
    int rr = t >> 4, cbl = t & 15;
    int cbg = cbl ^ rr;
    #pragma unroll
    for (int r = 0; r < 4; r++) {
      int row_l = r * 16 + rr;
      int ra = imin(i0g + row_l, iend - 1);
      int rb = imin(j0g + row_l, jend - 1);
      gA[r] = (const char*)(Xg + (size_t)ra * K) + cbg * 16;
      gB[r] = (const char*)(Xg + (size_t)rb * K) + cbg * 16;
    }

    // Fragment LDS byte offsets: row*256 + (cb ^ (row&15))*16, row&15 == lr.
    int aoff[2][4], boff[2][4];
    #pragma unroll
    for (int ti = 0; ti < 2; ti++)
      #pragma unroll
      for (int kc = 0; kc < 4; kc++) {
        int cb = kc * 4 + quad;
        int sw = (cb ^ lr) * 16;
        aoff[ti][kc] = (wi * 32 + ti * 16 + lr) * 256 + sw;
        boff[ti][kc] = (wj * 32 + ti * 16 + lr) * 256 + sw;
      }

    f32x4 acc[2][2];
    acc[0][0] = (f32x4)0.f; acc[0][1] = (f32x4)0.f;
    acc[1][0] = (f32x4)0.f; acc[1][1] = (f32x4)0.f;

    auto stage = [&](int buf, int itk) {
      int koff = itk * (BK * 2);
      char* la = (char*)sA + buf * 16384 + t * 16;
      char* lb = (char*)sB + buf * 16384 + t * 16;
      #pragma unroll
      for (int r = 0; r < 4; r++) {
        glds16(gA[r] + koff, la + r * 4096);
        glds16(gB[r] + koff, lb + r * 4096);
      }
    };

    auto compute = [&](int buf) {
      const char* bufA = (const char*)sA + buf * 16384;
      const char* bufB = (const char*)sB + buf * 16384;
      #pragma unroll
      for (int kc = 0; kc < 4; kc++) {
        bf16x8 a0 = *(const bf16x8*)(bufA + aoff[0][kc]);
        bf16x8 a1 = *(const bf16x8*)(bufA + aoff[1][kc]);
        bf16x8 b0 = *(const bf16x8*)(bufB + boff[0][kc]);
        bf16x8 b1 = *(const bf16x8*)(bufB + boff[1][kc]);
        acc[0][0] = __builtin_amdgcn_mfma_f32_16x16x32_bf16(a0, b0, acc[0][0], 0, 0, 0);
        acc[0][1] = __builtin_amdgcn_mfma_f32_16x16x32_bf16(a0, b1, acc[0][1], 0, 0, 0);
        acc[1][0] = __builtin_amdgcn_mfma_f32_16x16x32_bf16(a1, b0, acc[1][0], 0, 0, 0);
        acc[1][1] = __builtin_amdgcn_mfma_f32_16x16x32_bf16(a1, b1, acc[1][1], 0, 0, 0);
      }
    };

    stage(0, 0);
    for (int itk = 0; itk < NITER - 1; ++itk) {
      int cur = itk & 1;
      __builtin_amdgcn_s_barrier();       // prev compute on buf[cur^1] done
      stage(cur ^ 1, itk + 1);            // 8 async loads, stay in flight
      __builtin_amdgcn_s_waitcnt(0x0F78); // vmcnt(8): cur's loads landed
      __builtin_amdgcn_s_barrier();       // all waves' cur loads landed
      __builtin_amdgcn_sched_barrier(0);
      compute(cur);
    }
    __builtin_amdgcn_s_barrier();
    __builtin_amdgcn_s_waitcnt(0x0F70);   // vmcnt(0)
    __builtin_amdgcn_s_barrier();
    __builtin_amdgcn_sched_barrier(0);
    compute((NITER - 1) & 1);

    // Epilogue. C/D layout: col = lane&15 (j), row = quad*4 + reg (i).
    int jgc[2]; float sqj[2];
    #pragma unroll
    for (int tj = 0; tj < 2; tj++) {
      int jg = j0g + wj * 32 + tj * 16 + lr;
      jgc[tj] = imin(jg, jend - 1);
      sqj[tj] = sqg[jgc[tj]];
    }

    if (diag) {
      #pragma unroll
      for (int ti = 0; ti < 2; ti++) {
        #pragma unroll
        for (int r = 0; r < 4; r++) {
          int ig = i0g + wi * 32 + ti * 16 + quad * 4 + r;
          int igc = imin(ig, iend - 1);
          float sqi = sqg[igc];
          float apm = 0.f;
          #pragma unroll
          for (int tj = 0; tj < 2; tj++) {
            float d2 = sqi + sqj[tj] - 2.f * acc[ti][tj][r];
            apm = fmaxf(apm, sqrtf(fmaxf(d2, 1e-12f)));
          }
          #pragma unroll
          for (int m = 1; m < 16; m <<= 1) apm = fmaxf(apm, __shfl_xor(apm, m));
          if (lr == 0) atomicMax(ap + igc, __float_as_uint(apm));
        }
      }
    } else {
      float colmin[2] = {INFINITY, INFINITY};
      #pragma unroll
      for (int ti = 0; ti < 2; ti++) {
        #pragma unroll
        for (int r = 0; r < 4; r++) {
          int ig = i0g + wi * 32 + ti * 16 + quad * 4 + r;
          int igc = imin(ig, iend - 1);
          float sqi = sqg[igc];
          float anm = INFINITY;
          #pragma unroll
          for (int tj = 0; tj < 2; tj++) {
            float d2 = sqi + sqj[tj] - 2.f * acc[ti][tj][r];
            float d = sqrtf(fmaxf(d2, 1e-12f));
            anm = fminf(anm, d);
            colmin[tj] = fminf(colmin[tj], d);
          }
          #pragma unroll
          for (int m = 1; m < 16; m <<= 1) anm = fminf(anm, __shfl_xor(anm, m));
          if (lr == 0) atomicMin(an + igc, __float_as_uint(anm));
        }
      }
      #pragma unroll
      for (int tj = 0; tj < 2; tj++) {
        float v = colmin[tj];
        v = fminf(v, __shfl_xor(v, 16));
        v = fminf(v, __shfl_xor(v, 32));
        if (quad == 0) atomicMin(an + jgc[tj], __float_as_uint(v));
      }
    }
  }

  // ---- last-block ticket: final loss reduction --------------------------
  __syncthreads();
  if (t == 0) {
    __threadfence();
    int ticket = __hip_atomic_fetch_add(done, 1, __ATOMIC_ACQ_REL,
                                        __HIP_MEMORY_SCOPE_AGENT);
    s_islast = (ticket == GRID - 1);
  }
  __syncthreads();
  if (s_islast) {
    int has = flag[0];
    float s = 0.f;
    for (int i = t; i < N; i += 256) {
      unsigned int au = __hip_atomic_load(ap + i, __ATOMIC_RELAXED,
                                          __HIP_MEMORY_SCOPE_AGENT);
      unsigned int nu = __hip_atomic_load(an + i, __ATOMIC_RELAXED,
                                          __HIP_MEMORY_SCOPE_AGENT);
      float a = __uint_as_float(au);
      float bb = has ? __uint_as_float(nu) : 0.f;
      s += fmaxf(a - bb + MARGIN, 0.f);
    }
    #pragma unroll
    for (int m = 32; m; m >>= 1) s += __shfl_xor(s, m);
    if ((t & 63) == 0) wred[t >> 6] = s;
    __syncthreads();
    if (t == 0) out[0] = (wred[0] + wred[1] + wred[2] + wred[3]) / (float)N;
  }
}

// ---------------------------------------------------------------------------
extern "C" void kernel_launch(void* const* d_in, const int* in_sizes, int n_in,
                              void* d_out, int out_size, void* d_ws,
                              size_t ws_size, hipStream_t stream) {
  const float* X = (const float*)d_in[0];
  const int* tg = (const int*)d_in[1];
  float* out = (float*)d_out;

  char* ws = (char*)d_ws;
  __bf16* Xg = (__bf16*)ws;
  size_t o = (size_t)N * K * 2;
  float* sqg = (float*)(ws + o); o += (size_t)N * 4;
  unsigned int* ap = (unsigned int*)(ws + o); o += (size_t)N * 4;
  unsigned int* an = (unsigned int*)(ws + o); o += (size_t)N * 4;
  int* cnt = (int*)(ws + o); o += NC * 4;
  int* off = (int*)(ws + o); o += NC * 4;
  int* cur = (int*)(ws + o); o += NC * 4;
  int* flag = (int*)(ws + o); o += 4;
  int* done = (int*)(ws + o); o += 4;

  hist_kernel<<<1, 256, 0, stream>>>(tg, cnt, off, cur, flag, done);
  convert_kernel<<<N, 256, 0, stream>>>(X, tg, Xg, sqg, ap, an, cur);
  gemm_reduce_kernel<<<GRID, 256, 0, stream>>>(Xg, sqg, cnt, off, ap, an,
                                               flag, done, out);
}